// Round 1
// baseline (81.610 us; speedup 1.0000x reference)
//
#include <hip/hip_runtime.h>
#include <hip/hip_fp16.h>

// Problem: B=2, N=1024, F_in=128, F_out=64
// out[b,i,f] = (1 - deg[b,i]) * xw[b,i,f] + sum_j w[b,i,j]*xw[b,j,f] + bias[f]
//   w[b,i,j] = adj[b,i,j] / max(L1(xw_i, xw_j), 1e-3), deg = row-sum of w
// Diagonal w_ii cancels identically in the output -> excluded from w and deg.
//
// R5: 64x64 (i,j) tiles, grid 512. Phase 1: packed-f16 L1 distances with 4x4
// register blocking + XOR-swizzled LDS (balanced banks). Phase 2: f16 MFMA.
// Partials stored f16 (half the reduce traffic). gemm k4-blocked.
// R6: divide -> v_rcp_f32 * mul (precision margin: f16 distances dominate);
//     finish_gtv vectorized 2-wide (half2/float2), grid 512 -> 256.

#define JS 16
#define HSTR 72    // f16 row stride: 144 B (16B-aligned; swizzle balances banks)

typedef _Float16 half4_t __attribute__((ext_vector_type(4)));
typedef _Float16 half8_t __attribute__((ext_vector_type(8)));
typedef float    f32x4_t __attribute__((ext_vector_type(4)));

// ---------------- Kernel 1: xw = x @ W; emit f32, f16, f16-transposed ----
__global__ __launch_bounds__(256) void gemm_xw(const float* __restrict__ x,
                                               const float* __restrict__ w,
                                               float* __restrict__ xw,
                                               __half* __restrict__ xwh,
                                               __half* __restrict__ xwt) {
    __shared__ float ws_[128 * 64];   // 32 KB
    __shared__ float xs[8 * 132];
    __shared__ __half ts[8 * 64];     // transpose staging
    const int tid = threadIdx.x;
    const int r0  = blockIdx.x * 8;   // 256 blocks x 8 rows

#pragma unroll
    for (int e = tid; e < 2048; e += 256)
        ((float4*)ws_)[e] = ((const float4*)w)[e];
    {
        int row = tid >> 5, c = tid & 31;
        float4 v = *(const float4*)&x[(size_t)(r0 + row) * 128 + c * 4];
        *(float4*)&xs[row * 132 + c * 4] = v;
    }
    __syncthreads();

    const int rl = tid >> 5;   // 0..7
    const int fg = tid & 31;   // 2 features
    float2 acc = {0.f, 0.f};
#pragma unroll
    for (int k4 = 0; k4 < 32; ++k4) {
        float4 xv = *(const float4*)&xs[rl * 132 + k4 * 4];
        const float* xp = &xv.x;
#pragma unroll
        for (int m = 0; m < 4; ++m) {
            float2 wv = *(const float2*)&ws_[(k4 * 4 + m) * 64 + 2 * fg];
            acc.x += xp[m] * wv.x; acc.y += xp[m] * wv.y;
        }
    }
    size_t o = (size_t)(r0 + rl) * 64 + 2 * fg;
    *(float2*)&xw[o] = acc;
    __half2 h2 = __floats2half2_rn(acc.x, acc.y);
    *(__half2*)&xwh[o] = h2;
    *(__half2*)&ts[rl * 64 + 2 * fg] = h2;
    __syncthreads();

    if (tid < 64) {
        const int f = tid;
        const int b = r0 >> 10;
        const int n0 = r0 & 1023;
        __half hv[8];
#pragma unroll
        for (int r = 0; r < 8; ++r) hv[r] = ts[r * 64 + f];
        *(half8_t*)&xwt[((size_t)(b * 64 + f)) * 1024 + n0] = *(half8_t*)hv;
    }
}

// ---------------- Kernel 2: fused distances + MFMA aggregation ----------------
template <bool ATOMIC>
__global__ __launch_bounds__(256) void fused_gtv(const __half* __restrict__ xwh,
                                                 const __half* __restrict__ xwt,
                                                 const float* __restrict__ adj,
                                                 __half* __restrict__ part,
                                                 float* __restrict__ aout,
                                                 float* __restrict__ pdeg) {
    __shared__ __half xih[64 * HSTR];   // 9 KB [i][f], 16B-block swizzled
    __shared__ __half xjh[64 * HSTR];   // 9 KB [j][f], swizzled
    __shared__ __half xjt[64 * HSTR];   // 9 KB [f][j], linear (MFMA B)
    __shared__ __half wt [64 * HSTR];   // 9 KB [i][j], linear (MFMA A)

    const int tid = threadIdx.x;
    const int bx  = blockIdx.x;
    const int js  = bx & 15;
    const int it  = (bx >> 4) & 15;
    const int b   = bx >> 8;
    const int i0  = it * 64;
    const int j0  = js * 64;

    const __half* xhb = xwh + (size_t)b * 65536;
    const __half* xtb = xwt + (size_t)b * 65536;
    const float*  adjb = adj + (size_t)b * 1048576;

    const int ty = tid >> 4;   // 0..15 -> i rows 4ty..4ty+3
    const int tx = tid & 15;   // 0..15 -> j cols 4tx..4tx+3

    // prefetch adj 4x4 block (16 lanes x 16B = 256B contiguous per row)
    float4 av[4];
#pragma unroll
    for (int r = 0; r < 4; ++r)
        av[r] = *(const float4*)&adjb[(size_t)(i0 + 4 * ty + r) * 1024 + j0 + 4 * tx];

    // stage xih/xjh (swizzled) + xjt (linear): 512 x 16B each, 2 per thread
#pragma unroll
    for (int e = tid; e < 512; e += 256) {
        int row = e >> 3, cb = e & 7;
        int sc = ((cb ^ ((row >> 2) & 7)) << 3);
        float4 vi = *(const float4*)&xhb[(i0 + row) * 64 + cb * 8];
        *(float4*)&xih[row * HSTR + sc] = vi;
        float4 vj = *(const float4*)&xhb[(j0 + row) * 64 + cb * 8];
        *(float4*)&xjh[row * HSTR + sc] = vj;
        float4 vt = *(const float4*)&xtb[row * 1024 + j0 + cb * 8];  // row = f
        *(float4*)&xjt[row * HSTR + cb * 8] = vt;
    }
    __syncthreads();

    // ---- phase 1: 4x4 pairwise L1 distances, packed f16 ----
    __half2 acc[4][4];
#pragma unroll
    for (int r = 0; r < 4; ++r)
#pragma unroll
        for (int q = 0; q < 4; ++q) acc[r][q] = __floats2half2_rn(0.f, 0.f);

#pragma unroll
    for (int c = 0; c < 8; ++c) {
        const int ca = ((c ^ (ty & 7)) << 3);
        const int cb = ((c ^ (tx & 7)) << 3);
        float4 a[4], bb[4];
#pragma unroll
        for (int r = 0; r < 4; ++r)
            a[r] = *(const float4*)&xih[(4 * ty + r) * HSTR + ca];
#pragma unroll
        for (int q = 0; q < 4; ++q)
            bb[q] = *(const float4*)&xjh[(4 * tx + q) * HSTR + cb];
#pragma unroll
        for (int r = 0; r < 4; ++r) {
            const __half2* pa = (const __half2*)&a[r];
#pragma unroll
            for (int q = 0; q < 4; ++q) {
                const __half2* pb = (const __half2*)&bb[q];
#pragma unroll
                for (int m = 0; m < 4; ++m)
                    acc[r][q] = __hadd2(acc[r][q], __habs2(__hsub2(pa[m], pb[m])));
            }
        }
    }

    // w = adj * rcp(max(d,1e-3)), diag excluded; write f16 wt[i][j]; deg via shfl
    // v_rcp_f32 (~1 ulp) error is negligible vs the f16 distance quantization.
    float dsum[4];
#pragma unroll
    for (int r = 0; r < 4; ++r) {
        const int gi = i0 + 4 * ty + r;
        float wv[4];
        dsum[r] = 0.f;
#pragma unroll
        for (int q = 0; q < 4; ++q) {
            float d = __low2float(acc[r][q]) + __high2float(acc[r][q]);
            float inv = __builtin_amdgcn_rcpf(fmaxf(d, 1e-3f));
            float v = (&av[r].x)[q] * inv;
            wv[q] = (gi == j0 + 4 * tx + q) ? 0.f : v;
            dsum[r] += wv[q];
        }
        float2 packed;
        ((__half2*)&packed)[0] = __floats2half2_rn(wv[0], wv[1]);
        ((__half2*)&packed)[1] = __floats2half2_rn(wv[2], wv[3]);
        *(float2*)&wt[(4 * ty + r) * HSTR + 4 * tx] = packed;
    }
#pragma unroll
    for (int r = 0; r < 4; ++r) {
#pragma unroll
        for (int m = 1; m < 16; m <<= 1)
            dsum[r] += __shfl_xor(dsum[r], m, 16);
    }
    if (tx == 0) {
#pragma unroll
        for (int r = 0; r < 4; ++r) {
            if (ATOMIC) atomicAdd(&pdeg[b * 1024 + i0 + 4 * ty + r], dsum[r]);
            else pdeg[(js * 2 + b) * 1024 + i0 + 4 * ty + r] = dsum[r];
        }
    }
    __syncthreads();

    // ---- phase 2: MFMA  P[64x64] = W[64xj64] x Xj[j64xf64] ----
    const int wv_  = tid >> 6;   // wave = m-tile
    const int lane = tid & 63;
    const int quad = lane >> 4;
    const int l15  = lane & 15;

    f32x4_t c[4] = {{0,0,0,0},{0,0,0,0},{0,0,0,0},{0,0,0,0}};
    half8_t a0 = *(half8_t*)&wt[(wv_ * 16 + l15) * HSTR + quad * 8];
    half8_t a1 = *(half8_t*)&wt[(wv_ * 16 + l15) * HSTR + 32 + quad * 8];
#pragma unroll
    for (int n = 0; n < 4; ++n) {
        half8_t b0 = *(half8_t*)&xjt[(n * 16 + l15) * HSTR + quad * 8];
        half8_t b1 = *(half8_t*)&xjt[(n * 16 + l15) * HSTR + 32 + quad * 8];
        c[n] = __builtin_amdgcn_mfma_f32_16x16x32_f16(a0, b0, c[n], 0, 0, 0);
        c[n] = __builtin_amdgcn_mfma_f32_16x16x32_f16(a1, b1, c[n], 0, 0, 0);
    }

    // epilogue: C row = wv_*16 + quad*4 + r, col = n*16 + l15
    if (ATOMIC) {
#pragma unroll
        for (int n = 0; n < 4; ++n)
#pragma unroll
            for (int r = 0; r < 4; ++r) {
                int row = wv_ * 16 + quad * 4 + r;
                atomicAdd(&aout[((size_t)b * 1024 + i0 + row) * 64 + n * 16 + l15], c[n][r]);
            }
    } else {
        const size_t slot = (size_t)(js * 2 + b) * 65536;
#pragma unroll
        for (int n = 0; n < 4; ++n)
#pragma unroll
            for (int r = 0; r < 4; ++r) {
                int row = wv_ * 16 + quad * 4 + r;
                part[slot + (i0 + row) * 64 + n * 16 + l15] = __float2half(c[n][r]);
            }
    }
}

// ---------------- Kernel 3: reduce partials + identity + bias ----------------
// Non-atomic path: 2-wide vectorized (half2 partial loads, float2 out), grid 256.
__global__ __launch_bounds__(256) void finish_gtv_v2(const float* __restrict__ xw,
                                                     const __half* __restrict__ part,
                                                     const float* __restrict__ pdeg,
                                                     const float* __restrict__ bias,
                                                     float* __restrict__ out) {
    int idx2 = blockIdx.x * 256 + threadIdx.x;  // 0..65535 float2 elements
    int f2 = idx2 & 31;          // half2 / float2 column index (f = 2*f2)
    int r  = idx2 >> 5;          // b*1024 + n
    int b  = r >> 10;
    int n  = r & 1023;

    float2 s = {0.f, 0.f};
    float dgs = 0.f;
    const __half2* p2 = (const __half2*)part;
#pragma unroll
    for (int js = 0; js < JS; ++js) {
        int sl = js * 2 + b;
        __half2 h = p2[(size_t)sl * 32768 + n * 32 + f2];
        float2 f = __half22float2(h);
        s.x += f.x; s.y += f.y;
        dgs += pdeg[sl * 1024 + n];
    }
    float2 xv = ((const float2*)xw)[idx2];
    float2 bv = ((const float2*)bias)[f2];
    float id = 1.f - dgs;
    float2 o;
    o.x = s.x + id * xv.x + bv.x;
    o.y = s.y + id * xv.y + bv.y;
    ((float2*)out)[idx2] = o;
}

__global__ __launch_bounds__(256) void finish_gtv_atomic(const float* __restrict__ xw,
                                                         const float* __restrict__ pdeg,
                                                         const float* __restrict__ bias,
                                                         float* __restrict__ out) {
    int idx = blockIdx.x * 256 + threadIdx.x;  // 0..131071
    int f = idx & 63;
    int r = idx >> 6;           // b*1024 + n
    out[idx] = out[idx] + (1.f - pdeg[r]) * xw[idx] + bias[f];
}

extern "C" void kernel_launch(void* const* d_in, const int* in_sizes, int n_in,
                              void* d_out, int out_size, void* d_ws, size_t ws_size,
                              hipStream_t stream) {
    const float* x    = (const float*)d_in[0];   // [2,1024,128]
    const float* adj  = (const float*)d_in[1];   // [2,1024,1024]
    const float* w    = (const float*)d_in[2];   // [128,64]
    const float* bias = (const float*)d_in[3];   // [64]
    float* out = (float*)d_out;                  // [2,1024,64]

    char* wsb = (char*)d_ws;
    float*  xw   = (float*)wsb;                      // 512 KB
    __half* xwh  = (__half*)(wsb + 512 * 1024);      // 256 KB  [b][n][f]
    __half* xwt  = (__half*)(wsb + 768 * 1024);      // 256 KB  [b][f][n]
    float*  pdeg = (float*)(wsb + 1024 * 1024);      // 128 KB (32 x 1024)
    __half* part = (__half*)(wsb + 1152 * 1024);     // 4 MB  (32 x 65536 f16)
    const size_t NEED = 1152 * 1024 + (size_t)32 * 65536 * 2;

    gemm_xw<<<256, 256, 0, stream>>>(x, w, xw, xwh, xwt);

    if (ws_size >= NEED) {
        fused_gtv<false><<<512, 256, 0, stream>>>(xwh, xwt, adj, part, nullptr, pdeg);
        finish_gtv_v2<<<256, 256, 0, stream>>>(xw, part, pdeg, bias, out);
    } else {
        hipMemsetAsync(out, 0, 2 * 1024 * 64 * sizeof(float), stream);
        hipMemsetAsync(pdeg, 0, 2 * 1024 * sizeof(float), stream);
        fused_gtv<true><<<512, 256, 0, stream>>>(xwh, xwt, adj, nullptr, out, pdeg);
        finish_gtv_atomic<<<512, 256, 0, stream>>>(xw, pdeg, bias, out);
    }
}